// Round 14
// baseline (360.119 us; speedup 1.0000x reference)
//
#include <hip/hip_runtime.h>
#include <float.h>
#include <math.h>

#define THREADS 256
#define CAP 1280

typedef float f32x4 __attribute__((ext_vector_type(4)));
typedef unsigned short u16;
typedef u16 u16x8 __attribute__((ext_vector_type(8)));

// (v, idx) comparator implementing lax.top_k order: larger value wins,
// ties broken by LOWER index. Strict total order (indices unique per row).
__device__ __forceinline__ bool better(float av, int ai, float bv, int bi) {
    return av > bv || (av == bv && ai < bi);
}

// wave-wide argmax on (v, ix); all 64 lanes receive the winner.
__device__ __forceinline__ void wave_argmax(float& v, int& ix) {
    #pragma unroll
    for (int m = 32; m >= 1; m >>= 1) {
        float ov = __shfl_xor(v, m, 64);
        int   oi = __shfl_xor(ix, m, 64);
        if (better(ov, oi, v, ix)) { v = ov; ix = oi; }
    }
}

// ---------------------------------------------------------------------------
// Deterministic block reductions for the softmax (4 waves of 64).
// ---------------------------------------------------------------------------
__device__ __forceinline__ void block_argmax(float& v, int& idx, float* wv, int* wi, int tid) {
    wave_argmax(v, idx);
    if ((tid & 63) == 0) { wv[tid >> 6] = v; wi[tid >> 6] = idx; }
    __syncthreads();
    if (tid == 0) {
        float bv = wv[0]; int bi = wi[0];
        #pragma unroll
        for (int w = 1; w < 4; ++w) {
            if (better(wv[w], wi[w], bv, bi)) { bv = wv[w]; bi = wi[w]; }
        }
        wv[0] = bv; wi[0] = bi;
    }
    __syncthreads();
    v = wv[0]; idx = wi[0];
    __syncthreads();
}

__device__ __forceinline__ float block_sum(float v, float* wv, int tid) {
    #pragma unroll
    for (int m = 32; m >= 1; m >>= 1) v += __shfl_xor(v, m, 64);
    if ((tid & 63) == 0) wv[tid >> 6] = v;
    __syncthreads();
    if (tid == 0) wv[0] = wv[0] + wv[1] + wv[2] + wv[3];
    __syncthreads();
    float r = wv[0];
    __syncthreads();
    return r;
}

// sorted-insert into a DESC-sorted register 8-list (static indexing only)
__device__ __forceinline__ void insert1(float* tv, int* ti, float v, int ix) {
    if (better(v, ix, tv[7], ti[7])) {
        tv[7] = v; ti[7] = ix;
        #pragma unroll
        for (int p = 7; p > 0; --p) {
            if (better(tv[p], ti[p], tv[p - 1], ti[p - 1])) {
                float tf = tv[p]; tv[p] = tv[p - 1]; tv[p - 1] = tf;
                int   tt = ti[p]; ti[p] = ti[p - 1]; ti[p - 1] = tt;
            }
        }
    }
}

// ---------------------------------------------------------------------------
// Fast exact block top-8 from per-thread DESC-sorted lists (R10-proven).
// 2 barriers, no serial sections; deterministic (unique indices).
// ---------------------------------------------------------------------------
__device__ void block_top8(float* tv, int* ti,
                           float (*crossv)[8], int (*crossi)[8],
                           float* t8v, int* t8i, int tid) {
    float w8v[8]; int w8i[8];
    #pragma unroll
    for (int r = 0; r < 8; ++r) {
        float v = tv[0]; int ix = ti[0];
        wave_argmax(v, ix);
        if (ti[0] == ix) {                  // unique owner pops its head
            #pragma unroll
            for (int p = 0; p < 7; ++p) { tv[p] = tv[p + 1]; ti[p] = ti[p + 1]; }
            tv[7] = -FLT_MAX; ti[7] = 0x7fffffff;
        }
        w8v[r] = v; w8i[r] = ix;            // static index r
    }
    const int wid = tid >> 6, lane = tid & 63;
    if (lane == 0) {
        #pragma unroll
        for (int k = 0; k < 8; ++k) { crossv[wid][k] = w8v[k]; crossi[wid][k] = w8i[k]; }
    }
    __syncthreads();
    float v  = (lane < 32) ? crossv[lane >> 3][lane & 7] : -FLT_MAX;
    int   ix = (lane < 32) ? crossi[lane >> 3][lane & 7] : 0x7fffffff;
    #pragma unroll
    for (int r = 0; r < 8; ++r) {
        float mv = v; int mi = ix;
        wave_argmax(mv, mi);
        if (ix == mi) { v = -FLT_MAX; ix = 0x7fffffff; }   // pop winner
        if (tid == 0) { t8v[r] = mv; t8i[r] = mi; }
    }
    __syncthreads();
}

__device__ __forceinline__ void scan4(const f32x4& val, int base, float thr,
                                      float* cbv, int* cbi, int* ccnt) {
    #pragma unroll
    for (int c = 0; c < 4; ++c) {
        if (val[c] >= thr) {              // >=: value-ties must compete by index
            int pos = atomicAdd(ccnt, 1);
            if (pos < CAP) { cbv[pos] = val[c]; cbi[pos] = base + c; }
        }
    }
}

// ---------------------------------------------------------------------------
// Kernel A: W[HH][S] fp32 -> Wtb[S][HH] bf16 (RNE).
// ---------------------------------------------------------------------------
__global__ __launch_bounds__(256) void transposeW_bf16(const float* __restrict__ W,
                                                       u16* __restrict__ Wtb,
                                                       int S, int HH) {
    __shared__ float tile[32][33];
    int x  = blockIdx.x * 32 + threadIdx.x;
    int y0 = blockIdx.y * 32;
    #pragma unroll
    for (int i = threadIdx.y; i < 32; i += 8) {
        int h = y0 + i;
        if (x < S && h < HH) tile[i][threadIdx.x] = W[(size_t)h * S + x];
    }
    __syncthreads();
    #pragma unroll
    for (int i = threadIdx.y; i < 32; i += 8) {
        int s = blockIdx.x * 32 + i;
        int h = y0 + threadIdx.x;
        if (s < S && h < HH) {
            unsigned u = __float_as_uint(tile[threadIdx.x][i]);
            unsigned r = (u + 0x7fffu + ((u >> 16) & 1u)) >> 16;   // RNE bf16
            Wtb[(size_t)s * HH + h] = (u16)r;
        }
    }
}

// ---------------------------------------------------------------------------
// Fused per-row kernel — IDENTICAL to R10 (354us, best) except loads are
// PLAIN while stores stay NONTEMPORAL (2x2 access-mode matrix completion:
// NT-store avoids write-allocate [R12: plain stores +57us]; plain loads ride
// the normal cache path, which may return faster than the NT bypass path).
// ---------------------------------------------------------------------------
__global__ __launch_bounds__(THREADS) void fused_row(const float* __restrict__ hidden,
                                                     const float* __restrict__ pg,
                                                     const u16* __restrict__ Wtb,
                                                     const float* __restrict__ bias,
                                                     const int* __restrict__ graph,
                                                     float* __restrict__ outg,
                                                     float* __restrict__ outS,
                                                     int S, int V, int NBR) {
    __shared__ __align__(16) float sh_h[256];
    __shared__ float cbv[CAP];
    __shared__ int   cbi[CAP];
    __shared__ float t8v[8];
    __shared__ int   t8i[8];
    __shared__ float crossv[4][8];
    __shared__ int   crossi[4][8];
    __shared__ int   hkey[512];
    __shared__ int   hval[512];
    __shared__ float slog[256];
    __shared__ int   ol_s[256];
    __shared__ int   ol_t[256];
    __shared__ float wv[4];
    __shared__ int   wi[4];
    __shared__ int   ccnt, ocnt;

    const int row = blockIdx.x, tid = threadIdx.x;
    const float LOGEPS = -18.420680743952367f;   // logf(1e-8f)

    sh_h[tid] = hidden[(size_t)row * 256 + tid];
    hkey[tid] = -1; hkey[tid + 256] = -1;
    hval[tid] = 0x7fffffff; hval[tid + 256] = 0x7fffffff;
    if (tid == 0) { ccnt = 0; ocnt = 0; }

    const f32x4* in4  = (const f32x4*)(pg   + (size_t)row * V);
    f32x4*       out4 = (f32x4*)(outg + (size_t)row * V);
    f32x4*       o4   = (f32x4*)(outS + (size_t)row * S);
    const f32x4 fill4 = { LOGEPS, LOGEPS, LOGEPS, LOGEPS };
    const int nv4 = V >> 2, nS4 = S >> 2;

    // ---- iteration 0: copy+fill first 1024 elements, seed per-thread lists
    float tv[8]; int ti[8];
    #pragma unroll
    for (int p = 0; p < 8; ++p) { tv[p] = -FLT_MAX; ti[p] = 0x7fffffff; }
    {
        f32x4 val = in4[tid];                            // plain load
        __builtin_nontemporal_store(val, out4 + tid);
        if (tid < nS4) __builtin_nontemporal_store(fill4, o4 + tid);
        #pragma unroll
        for (int c = 0; c < 4; ++c) insert1(tv, ti, val[c], (tid << 2) | c);
    }
    __syncthreads();                       // hash init + sh_h also done
    block_top8(tv, ti, crossv, crossi, t8v, t8i, tid);    // 2 barriers
    const float thr = t8v[7];              // conservative: subset 8th <= row 8th

    // ---- main stream loop: barrier-free, 4 loads in flight, cheap scan
    int i = THREADS + tid;
    for (; i + 3 * THREADS < nv4; i += 4 * THREADS) {
        f32x4 a = in4[i];                                // plain loads
        f32x4 b = in4[i + THREADS];
        f32x4 c = in4[i + 2 * THREADS];
        f32x4 d = in4[i + 3 * THREADS];
        __builtin_nontemporal_store(a, out4 + i);
        __builtin_nontemporal_store(b, out4 + i + THREADS);
        __builtin_nontemporal_store(c, out4 + i + 2 * THREADS);
        __builtin_nontemporal_store(d, out4 + i + 3 * THREADS);
        if (i < nS4)               __builtin_nontemporal_store(fill4, o4 + i);
        if (i + THREADS < nS4)     __builtin_nontemporal_store(fill4, o4 + i + THREADS);
        if (i + 2 * THREADS < nS4) __builtin_nontemporal_store(fill4, o4 + i + 2 * THREADS);
        if (i + 3 * THREADS < nS4) __builtin_nontemporal_store(fill4, o4 + i + 3 * THREADS);
        scan4(a, i << 2, thr, cbv, cbi, &ccnt);
        scan4(b, (i + THREADS) << 2, thr, cbv, cbi, &ccnt);
        scan4(c, (i + 2 * THREADS) << 2, thr, cbv, cbi, &ccnt);
        scan4(d, (i + 3 * THREADS) << 2, thr, cbv, cbi, &ccnt);
    }
    for (; i < nv4; i += THREADS) {
        f32x4 a = in4[i];                                // plain load
        __builtin_nontemporal_store(a, out4 + i);
        if (i < nS4) __builtin_nontemporal_store(fill4, o4 + i);
        scan4(a, i << 2, thr, cbv, cbi, &ccnt);
    }
    for (int q = nv4 + tid; q < nS4; q += THREADS)        // S > V leftover (none)
        __builtin_nontemporal_store(fill4, o4 + q);
    for (int i2 = (nv4 << 2) + tid; i2 < V; i2 += THREADS) {  // scalar tails (none)
        float v = pg[(size_t)row * V + i2];
        outg[(size_t)row * V + i2] = v;
        if (v >= thr) {
            int pos = atomicAdd(&ccnt, 1);
            if (pos < CAP) { cbv[pos] = v; cbi[pos] = i2; }
        }
    }
    for (int i2 = (nS4 << 2) + tid; i2 < S; i2 += THREADS)
        outS[(size_t)row * S + i2] = LOGEPS;
    __syncthreads();

    // ---- final exact top-8: merge seed t8 with appended candidates
    const int cc = ccnt;
    #pragma unroll
    for (int p = 0; p < 8; ++p) { tv[p] = -FLT_MAX; ti[p] = 0x7fffffff; }
    if (cc <= CAP) {
        for (int k = tid; k < 8 + cc; k += THREADS) {     // virtual [t8 | cbuf]
            float v; int ix;
            if (k < 8) { v = t8v[k]; ix = t8i[k]; } else { v = cbv[k - 8]; ix = cbi[k - 8]; }
            insert1(tv, ti, v, ix);
        }
    } else {
        // overflow fallback (astronomically rare): exact full re-scan
        for (int q = tid; q < nv4; q += THREADS) {
            f32x4 val = in4[q];
            #pragma unroll
            for (int c = 0; c < 4; ++c) insert1(tv, ti, val[c], (q << 2) | c);
        }
        for (int i2 = (nv4 << 2) + tid; i2 < V; i2 += THREADS)
            insert1(tv, ti, pg[(size_t)row * V + i2], i2);
    }
    __syncthreads();                        // t8 fully consumed before overwrite
    block_top8(tv, ti, crossv, crossi, t8v, t8i, tid);    // 2 barriers

    // ---- gather candidate neighbours: 8 topk rows x 32 nbrs, coalesced
    const int j8 = tid >> 5, c32 = tid & 31;
    int my = -1;
    if (c32 < NBR) {
        int g = graph[(size_t)(t8i[j8] + S) * NBR + c32] - 1;
        my = (g >= 0 && g < S) ? g : -1;
    }

    // ---- hash dedup: owner = min tid per sense (order-independent).
    //      Each key claims exactly one slot (CAS); lookup is by key, so
    //      placement races are benign.
    if (my >= 0) {
        unsigned h = (((unsigned)my * 2654435761u) >> 23) & 511u;
        while (true) {
            int k = atomicCAS(&hkey[h], -1, my);
            if (k == -1 || k == my) { atomicMin(&hval[h], tid); break; }
            h = (h + 1) & 511u;
        }
    }
    __syncthreads();
    bool owner = false;
    if (my >= 0) {
        unsigned h = (((unsigned)my * 2654435761u) >> 23) & 511u;
        while (hkey[h] != my) h = (h + 1) & 511u;
        owner = (hval[h] == tid);
    }
    if (owner) {
        int pos = atomicAdd(&ocnt, 1);      // order nondet; results keyed by slot
        ol_s[pos] = my; ol_t[pos] = tid;
    }
    __syncthreads();
    int nsel = ocnt;
    if (nsel == 0) {                        // zero-neighbour fallback: sense 0
        if (tid == 0) { ol_s[0] = 0; ol_t[0] = 0; owner = true; my = 0; }
        nsel = 1;
        __syncthreads();
    }
    const int nowners = nsel;

    // ---- bf16 dots, 4 owners per 32-lane half per iteration (4 loads in
    //      flight -> L2/L3 latency amortized). logit -> slog[original slot].
    {
        const int halfId = tid >> 5;        // 0..7
        const int l32    = tid & 31;
        const f32x4 hA = ((const f32x4*)sh_h)[l32 * 2];
        const f32x4 hB = ((const f32x4*)sh_h)[l32 * 2 + 1];
        for (int o = halfId; o < nowners; o += 32) {
            const bool h1 = (o + 8)  < nowners;
            const bool h2 = (o + 16) < nowners;
            const bool h3 = (o + 24) < nowners;
            const int s0 = ol_s[o];
            const int s1 = h1 ? ol_s[o + 8]  : s0;
            const int s2 = h2 ? ol_s[o + 16] : s0;
            const int s3 = h3 ? ol_s[o + 24] : s0;
            const u16x8 w0 = *(const u16x8*)(Wtb + (size_t)s0 * 256 + l32 * 8);
            const u16x8 w1 = *(const u16x8*)(Wtb + (size_t)s1 * 256 + l32 * 8);
            const u16x8 w2 = *(const u16x8*)(Wtb + (size_t)s2 * 256 + l32 * 8);
            const u16x8 w3 = *(const u16x8*)(Wtb + (size_t)s3 * 256 + l32 * 8);
            float a0 = 0.f, a1 = 0.f, a2 = 0.f, a3 = 0.f;
            #pragma unroll
            for (int c = 0; c < 8; ++c) {
                const float hf = (c < 4) ? hA[c] : hB[c - 4];
                a0 = fmaf(__uint_as_float(((unsigned)w0[c]) << 16), hf, a0);
                a1 = fmaf(__uint_as_float(((unsigned)w1[c]) << 16), hf, a1);
                a2 = fmaf(__uint_as_float(((unsigned)w2[c]) << 16), hf, a2);
                a3 = fmaf(__uint_as_float(((unsigned)w3[c]) << 16), hf, a3);
            }
            #pragma unroll
            for (int m = 16; m >= 1; m >>= 1) {
                a0 += __shfl_xor(a0, m, 64);
                a1 += __shfl_xor(a1, m, 64);
                a2 += __shfl_xor(a2, m, 64);
                a3 += __shfl_xor(a3, m, 64);
            }
            const float b0 = bias[s0];
            const float b1 = bias[s1];
            const float b2 = bias[s2];
            const float b3 = bias[s3];
            if (l32 == 0) {
                slog[ol_t[o]] = a0 + b0;
                if (h1) slog[ol_t[o + 8]]  = a1 + b1;
                if (h2) slog[ol_t[o + 16]] = a2 + b2;
                if (h3) slog[ol_t[o + 24]] = a3 + b3;
            }
        }
    }
    __syncthreads();

    // ---- slot-ordered softmax (deterministic), delta at argmax, scatter
    const float logit = owner ? slog[tid] : -FLT_MAX;
    float mv = logit;
    int   ai = owner ? my : 0x7fffffff;
    block_argmax(mv, ai, wv, wi, tid);      // tie -> lowest sense (ref argmax)

    const float e = owner ? expf(logit - mv) : 0.f;
    const float sum = block_sum(e, wv, tid);
    // barriers above drained the fill stores (vmcnt(0) before s_barrier)
    // -> scatter below safely overwrites filled lanes of this row.
    if (owner) {
        float p = e / sum;
        if (my == ai) p -= 1e-8f * (float)(S - nsel);
        outS[(size_t)row * S + my] = logf(p);
    }
}

// ---------------------------------------------------------------------------
extern "C" void kernel_launch(void* const* d_in, const int* in_sizes, int n_in,
                              void* d_out, int out_size, void* d_ws, size_t ws_size,
                              hipStream_t stream) {
    const float* hidden = (const float*)d_in[0];
    const float* pg     = (const float*)d_in[1];
    const float* W      = (const float*)d_in[2];
    const float* bias   = (const float*)d_in[3];
    const int*   graph  = (const int*)d_in[4];
    // d_in[5] is K; fixed at 8 by the problem spec.

    const int S   = in_sizes[3];
    const int HH  = in_sizes[2] / S;   // 256
    const int N   = in_sizes[0] / HH;
    const int V   = in_sizes[1] / N;
    const int NBR = in_sizes[4] / (S + V);

    u16* Wtb = (u16*)d_ws;             // S*HH bf16

    float* outg = (float*)d_out;
    float* outS = outg + (size_t)N * V;

    dim3 tb(32, 8);
    dim3 tg((S + 31) / 32, (HH + 31) / 32);
    transposeW_bf16<<<tg, tb, 0, stream>>>(W, Wtb, S, HH);
    fused_row<<<N, THREADS, 0, stream>>>(hidden, pg, Wtb, bias, graph,
                                         outg, outS, S, V, NBR);
}

// Round 15
// 353.412 us; speedup vs baseline: 1.0190x; 1.0190x over previous
//
#include <hip/hip_runtime.h>
#include <float.h>
#include <math.h>

#define THREADS 256
#define CAP 1280

typedef float f32x4 __attribute__((ext_vector_type(4)));
typedef unsigned short u16;
typedef u16 u16x8 __attribute__((ext_vector_type(8)));

// (v, idx) comparator implementing lax.top_k order: larger value wins,
// ties broken by LOWER index. Strict total order (indices unique per row).
__device__ __forceinline__ bool better(float av, int ai, float bv, int bi) {
    return av > bv || (av == bv && ai < bi);
}

// wave-wide argmax on (v, ix); all 64 lanes receive the winner.
__device__ __forceinline__ void wave_argmax(float& v, int& ix) {
    #pragma unroll
    for (int m = 32; m >= 1; m >>= 1) {
        float ov = __shfl_xor(v, m, 64);
        int   oi = __shfl_xor(ix, m, 64);
        if (better(ov, oi, v, ix)) { v = ov; ix = oi; }
    }
}

// ---------------------------------------------------------------------------
// Deterministic block reductions for the softmax (4 waves of 64).
// ---------------------------------------------------------------------------
__device__ __forceinline__ void block_argmax(float& v, int& idx, float* wv, int* wi, int tid) {
    wave_argmax(v, idx);
    if ((tid & 63) == 0) { wv[tid >> 6] = v; wi[tid >> 6] = idx; }
    __syncthreads();
    if (tid == 0) {
        float bv = wv[0]; int bi = wi[0];
        #pragma unroll
        for (int w = 1; w < 4; ++w) {
            if (better(wv[w], wi[w], bv, bi)) { bv = wv[w]; bi = wi[w]; }
        }
        wv[0] = bv; wi[0] = bi;
    }
    __syncthreads();
    v = wv[0]; idx = wi[0];
    __syncthreads();
}

__device__ __forceinline__ float block_sum(float v, float* wv, int tid) {
    #pragma unroll
    for (int m = 32; m >= 1; m >>= 1) v += __shfl_xor(v, m, 64);
    if ((tid & 63) == 0) wv[tid >> 6] = v;
    __syncthreads();
    if (tid == 0) wv[0] = wv[0] + wv[1] + wv[2] + wv[3];
    __syncthreads();
    float r = wv[0];
    __syncthreads();
    return r;
}

// sorted-insert into a DESC-sorted register 8-list (static indexing only)
__device__ __forceinline__ void insert1(float* tv, int* ti, float v, int ix) {
    if (better(v, ix, tv[7], ti[7])) {
        tv[7] = v; ti[7] = ix;
        #pragma unroll
        for (int p = 7; p > 0; --p) {
            if (better(tv[p], ti[p], tv[p - 1], ti[p - 1])) {
                float tf = tv[p]; tv[p] = tv[p - 1]; tv[p - 1] = tf;
                int   tt = ti[p]; ti[p] = ti[p - 1]; ti[p - 1] = tt;
            }
        }
    }
}

// ---------------------------------------------------------------------------
// Fast exact block top-8 from per-thread DESC-sorted lists (R10-proven).
// 2 barriers, no serial sections; deterministic (unique indices).
// ---------------------------------------------------------------------------
__device__ void block_top8(float* tv, int* ti,
                           float (*crossv)[8], int (*crossi)[8],
                           float* t8v, int* t8i, int tid) {
    float w8v[8]; int w8i[8];
    #pragma unroll
    for (int r = 0; r < 8; ++r) {
        float v = tv[0]; int ix = ti[0];
        wave_argmax(v, ix);
        if (ti[0] == ix) {                  // unique owner pops its head
            #pragma unroll
            for (int p = 0; p < 7; ++p) { tv[p] = tv[p + 1]; ti[p] = ti[p + 1]; }
            tv[7] = -FLT_MAX; ti[7] = 0x7fffffff;
        }
        w8v[r] = v; w8i[r] = ix;            // static index r
    }
    const int wid = tid >> 6, lane = tid & 63;
    if (lane == 0) {
        #pragma unroll
        for (int k = 0; k < 8; ++k) { crossv[wid][k] = w8v[k]; crossi[wid][k] = w8i[k]; }
    }
    __syncthreads();
    float v  = (lane < 32) ? crossv[lane >> 3][lane & 7] : -FLT_MAX;
    int   ix = (lane < 32) ? crossi[lane >> 3][lane & 7] : 0x7fffffff;
    #pragma unroll
    for (int r = 0; r < 8; ++r) {
        float mv = v; int mi = ix;
        wave_argmax(mv, mi);
        if (ix == mi) { v = -FLT_MAX; ix = 0x7fffffff; }   // pop winner
        if (tid == 0) { t8v[r] = mv; t8i[r] = mi; }
    }
    __syncthreads();
}

__device__ __forceinline__ void scan4(const f32x4& val, int base, float thr,
                                      float* cbv, int* cbi, int* ccnt) {
    #pragma unroll
    for (int c = 0; c < 4; ++c) {
        if (val[c] >= thr) {              // >=: value-ties must compete by index
            int pos = atomicAdd(ccnt, 1);
            if (pos < CAP) { cbv[pos] = val[c]; cbi[pos] = base + c; }
        }
    }
}

// ---------------------------------------------------------------------------
// Kernel A: W[HH][S] fp32 -> Wtb[S][HH] bf16 (RNE).
// ---------------------------------------------------------------------------
__global__ __launch_bounds__(256) void transposeW_bf16(const float* __restrict__ W,
                                                       u16* __restrict__ Wtb,
                                                       int S, int HH) {
    __shared__ float tile[32][33];
    int x  = blockIdx.x * 32 + threadIdx.x;
    int y0 = blockIdx.y * 32;
    #pragma unroll
    for (int i = threadIdx.y; i < 32; i += 8) {
        int h = y0 + i;
        if (x < S && h < HH) tile[i][threadIdx.x] = W[(size_t)h * S + x];
    }
    __syncthreads();
    #pragma unroll
    for (int i = threadIdx.y; i < 32; i += 8) {
        int s = blockIdx.x * 32 + i;
        int h = y0 + threadIdx.x;
        if (s < S && h < HH) {
            unsigned u = __float_as_uint(tile[threadIdx.x][i]);
            unsigned r = (u + 0x7fffu + ((u >> 16) & 1u)) >> 16;   // RNE bf16
            Wtb[(size_t)s * HH + h] = (u16)r;
        }
    }
}

// ---------------------------------------------------------------------------
// Fused per-row kernel — R10 (353.8us, session best), restored byte-for-byte.
// NT loads + NT stores (NT stores avoid write-allocate RFO: plain stores
// regressed +57us in R12; plain loads were -6us in R14 — both NT is best).
// Stream: copy + fill + cheap threshold scan. Epilogue: 2-barrier block
// top-8, hash dedup (min-tid owner), ILP-4 bf16 dots, slot-ordered softmax.
// ---------------------------------------------------------------------------
__global__ __launch_bounds__(THREADS) void fused_row(const float* __restrict__ hidden,
                                                     const float* __restrict__ pg,
                                                     const u16* __restrict__ Wtb,
                                                     const float* __restrict__ bias,
                                                     const int* __restrict__ graph,
                                                     float* __restrict__ outg,
                                                     float* __restrict__ outS,
                                                     int S, int V, int NBR) {
    __shared__ __align__(16) float sh_h[256];
    __shared__ float cbv[CAP];
    __shared__ int   cbi[CAP];
    __shared__ float t8v[8];
    __shared__ int   t8i[8];
    __shared__ float crossv[4][8];
    __shared__ int   crossi[4][8];
    __shared__ int   hkey[512];
    __shared__ int   hval[512];
    __shared__ float slog[256];
    __shared__ int   ol_s[256];
    __shared__ int   ol_t[256];
    __shared__ float wv[4];
    __shared__ int   wi[4];
    __shared__ int   ccnt, ocnt;

    const int row = blockIdx.x, tid = threadIdx.x;
    const float LOGEPS = -18.420680743952367f;   // logf(1e-8f)

    sh_h[tid] = hidden[(size_t)row * 256 + tid];
    hkey[tid] = -1; hkey[tid + 256] = -1;
    hval[tid] = 0x7fffffff; hval[tid + 256] = 0x7fffffff;
    if (tid == 0) { ccnt = 0; ocnt = 0; }

    const f32x4* in4  = (const f32x4*)(pg   + (size_t)row * V);
    f32x4*       out4 = (f32x4*)(outg + (size_t)row * V);
    f32x4*       o4   = (f32x4*)(outS + (size_t)row * S);
    const f32x4 fill4 = { LOGEPS, LOGEPS, LOGEPS, LOGEPS };
    const int nv4 = V >> 2, nS4 = S >> 2;

    // ---- iteration 0: copy+fill first 1024 elements, seed per-thread lists
    float tv[8]; int ti[8];
    #pragma unroll
    for (int p = 0; p < 8; ++p) { tv[p] = -FLT_MAX; ti[p] = 0x7fffffff; }
    {
        f32x4 val = __builtin_nontemporal_load(in4 + tid);
        __builtin_nontemporal_store(val, out4 + tid);
        if (tid < nS4) __builtin_nontemporal_store(fill4, o4 + tid);
        #pragma unroll
        for (int c = 0; c < 4; ++c) insert1(tv, ti, val[c], (tid << 2) | c);
    }
    __syncthreads();                       // hash init + sh_h also done
    block_top8(tv, ti, crossv, crossi, t8v, t8i, tid);    // 2 barriers
    const float thr = t8v[7];              // conservative: subset 8th <= row 8th

    // ---- main stream loop: barrier-free, 4 loads in flight, cheap scan
    int i = THREADS + tid;
    for (; i + 3 * THREADS < nv4; i += 4 * THREADS) {
        f32x4 a = __builtin_nontemporal_load(in4 + i);
        f32x4 b = __builtin_nontemporal_load(in4 + i + THREADS);
        f32x4 c = __builtin_nontemporal_load(in4 + i + 2 * THREADS);
        f32x4 d = __builtin_nontemporal_load(in4 + i + 3 * THREADS);
        __builtin_nontemporal_store(a, out4 + i);
        __builtin_nontemporal_store(b, out4 + i + THREADS);
        __builtin_nontemporal_store(c, out4 + i + 2 * THREADS);
        __builtin_nontemporal_store(d, out4 + i + 3 * THREADS);
        if (i < nS4)               __builtin_nontemporal_store(fill4, o4 + i);
        if (i + THREADS < nS4)     __builtin_nontemporal_store(fill4, o4 + i + THREADS);
        if (i + 2 * THREADS < nS4) __builtin_nontemporal_store(fill4, o4 + i + 2 * THREADS);
        if (i + 3 * THREADS < nS4) __builtin_nontemporal_store(fill4, o4 + i + 3 * THREADS);
        scan4(a, i << 2, thr, cbv, cbi, &ccnt);
        scan4(b, (i + THREADS) << 2, thr, cbv, cbi, &ccnt);
        scan4(c, (i + 2 * THREADS) << 2, thr, cbv, cbi, &ccnt);
        scan4(d, (i + 3 * THREADS) << 2, thr, cbv, cbi, &ccnt);
    }
    for (; i < nv4; i += THREADS) {
        f32x4 a = __builtin_nontemporal_load(in4 + i);
        __builtin_nontemporal_store(a, out4 + i);
        if (i < nS4) __builtin_nontemporal_store(fill4, o4 + i);
        scan4(a, i << 2, thr, cbv, cbi, &ccnt);
    }
    for (int q = nv4 + tid; q < nS4; q += THREADS)        // S > V leftover (none)
        __builtin_nontemporal_store(fill4, o4 + q);
    for (int i2 = (nv4 << 2) + tid; i2 < V; i2 += THREADS) {  // scalar tails (none)
        float v = pg[(size_t)row * V + i2];
        outg[(size_t)row * V + i2] = v;
        if (v >= thr) {
            int pos = atomicAdd(&ccnt, 1);
            if (pos < CAP) { cbv[pos] = v; cbi[pos] = i2; }
        }
    }
    for (int i2 = (nS4 << 2) + tid; i2 < S; i2 += THREADS)
        outS[(size_t)row * S + i2] = LOGEPS;
    __syncthreads();

    // ---- final exact top-8: merge seed t8 with appended candidates
    const int cc = ccnt;
    #pragma unroll
    for (int p = 0; p < 8; ++p) { tv[p] = -FLT_MAX; ti[p] = 0x7fffffff; }
    if (cc <= CAP) {
        for (int k = tid; k < 8 + cc; k += THREADS) {     // virtual [t8 | cbuf]
            float v; int ix;
            if (k < 8) { v = t8v[k]; ix = t8i[k]; } else { v = cbv[k - 8]; ix = cbi[k - 8]; }
            insert1(tv, ti, v, ix);
        }
    } else {
        // overflow fallback (astronomically rare): exact full re-scan
        for (int q = tid; q < nv4; q += THREADS) {
            f32x4 val = in4[q];
            #pragma unroll
            for (int c = 0; c < 4; ++c) insert1(tv, ti, val[c], (q << 2) | c);
        }
        for (int i2 = (nv4 << 2) + tid; i2 < V; i2 += THREADS)
            insert1(tv, ti, pg[(size_t)row * V + i2], i2);
    }
    __syncthreads();                        // t8 fully consumed before overwrite
    block_top8(tv, ti, crossv, crossi, t8v, t8i, tid);    // 2 barriers

    // ---- gather candidate neighbours: 8 topk rows x 32 nbrs, coalesced
    const int j8 = tid >> 5, c32 = tid & 31;
    int my = -1;
    if (c32 < NBR) {
        int g = graph[(size_t)(t8i[j8] + S) * NBR + c32] - 1;
        my = (g >= 0 && g < S) ? g : -1;
    }

    // ---- hash dedup: owner = min tid per sense (order-independent).
    //      Each key claims exactly one slot (CAS); lookup is by key, so
    //      placement races are benign.
    if (my >= 0) {
        unsigned h = (((unsigned)my * 2654435761u) >> 23) & 511u;
        while (true) {
            int k = atomicCAS(&hkey[h], -1, my);
            if (k == -1 || k == my) { atomicMin(&hval[h], tid); break; }
            h = (h + 1) & 511u;
        }
    }
    __syncthreads();
    bool owner = false;
    if (my >= 0) {
        unsigned h = (((unsigned)my * 2654435761u) >> 23) & 511u;
        while (hkey[h] != my) h = (h + 1) & 511u;
        owner = (hval[h] == tid);
    }
    if (owner) {
        int pos = atomicAdd(&ocnt, 1);      // order nondet; results keyed by slot
        ol_s[pos] = my; ol_t[pos] = tid;
    }
    __syncthreads();
    int nsel = ocnt;
    if (nsel == 0) {                        // zero-neighbour fallback: sense 0
        if (tid == 0) { ol_s[0] = 0; ol_t[0] = 0; owner = true; my = 0; }
        nsel = 1;
        __syncthreads();
    }
    const int nowners = nsel;

    // ---- bf16 dots, 4 owners per 32-lane half per iteration (4 loads in
    //      flight -> L2/L3 latency amortized). logit -> slog[original slot].
    {
        const int halfId = tid >> 5;        // 0..7
        const int l32    = tid & 31;
        const f32x4 hA = ((const f32x4*)sh_h)[l32 * 2];
        const f32x4 hB = ((const f32x4*)sh_h)[l32 * 2 + 1];
        for (int o = halfId; o < nowners; o += 32) {
            const bool h1 = (o + 8)  < nowners;
            const bool h2 = (o + 16) < nowners;
            const bool h3 = (o + 24) < nowners;
            const int s0 = ol_s[o];
            const int s1 = h1 ? ol_s[o + 8]  : s0;
            const int s2 = h2 ? ol_s[o + 16] : s0;
            const int s3 = h3 ? ol_s[o + 24] : s0;
            const u16x8 w0 = *(const u16x8*)(Wtb + (size_t)s0 * 256 + l32 * 8);
            const u16x8 w1 = *(const u16x8*)(Wtb + (size_t)s1 * 256 + l32 * 8);
            const u16x8 w2 = *(const u16x8*)(Wtb + (size_t)s2 * 256 + l32 * 8);
            const u16x8 w3 = *(const u16x8*)(Wtb + (size_t)s3 * 256 + l32 * 8);
            float a0 = 0.f, a1 = 0.f, a2 = 0.f, a3 = 0.f;
            #pragma unroll
            for (int c = 0; c < 8; ++c) {
                const float hf = (c < 4) ? hA[c] : hB[c - 4];
                a0 = fmaf(__uint_as_float(((unsigned)w0[c]) << 16), hf, a0);
                a1 = fmaf(__uint_as_float(((unsigned)w1[c]) << 16), hf, a1);
                a2 = fmaf(__uint_as_float(((unsigned)w2[c]) << 16), hf, a2);
                a3 = fmaf(__uint_as_float(((unsigned)w3[c]) << 16), hf, a3);
            }
            #pragma unroll
            for (int m = 16; m >= 1; m >>= 1) {
                a0 += __shfl_xor(a0, m, 64);
                a1 += __shfl_xor(a1, m, 64);
                a2 += __shfl_xor(a2, m, 64);
                a3 += __shfl_xor(a3, m, 64);
            }
            const float b0 = bias[s0];
            const float b1 = bias[s1];
            const float b2 = bias[s2];
            const float b3 = bias[s3];
            if (l32 == 0) {
                slog[ol_t[o]] = a0 + b0;
                if (h1) slog[ol_t[o + 8]]  = a1 + b1;
                if (h2) slog[ol_t[o + 16]] = a2 + b2;
                if (h3) slog[ol_t[o + 24]] = a3 + b3;
            }
        }
    }
    __syncthreads();

    // ---- slot-ordered softmax (deterministic), delta at argmax, scatter
    const float logit = owner ? slog[tid] : -FLT_MAX;
    float mv = logit;
    int   ai = owner ? my : 0x7fffffff;
    block_argmax(mv, ai, wv, wi, tid);      // tie -> lowest sense (ref argmax)

    const float e = owner ? expf(logit - mv) : 0.f;
    const float sum = block_sum(e, wv, tid);
    // barriers above drained the fill stores (vmcnt(0) before s_barrier)
    // -> scatter below safely overwrites filled lanes of this row.
    if (owner) {
        float p = e / sum;
        if (my == ai) p -= 1e-8f * (float)(S - nsel);
        outS[(size_t)row * S + my] = logf(p);
    }
}

// ---------------------------------------------------------------------------
extern "C" void kernel_launch(void* const* d_in, const int* in_sizes, int n_in,
                              void* d_out, int out_size, void* d_ws, size_t ws_size,
                              hipStream_t stream) {
    const float* hidden = (const float*)d_in[0];
    const float* pg     = (const float*)d_in[1];
    const float* W      = (const float*)d_in[2];
    const float* bias   = (const float*)d_in[3];
    const int*   graph  = (const int*)d_in[4];
    // d_in[5] is K; fixed at 8 by the problem spec.

    const int S   = in_sizes[3];
    const int HH  = in_sizes[2] / S;   // 256
    const int N   = in_sizes[0] / HH;
    const int V   = in_sizes[1] / N;
    const int NBR = in_sizes[4] / (S + V);

    u16* Wtb = (u16*)d_ws;             // S*HH bf16

    float* outg = (float*)d_out;
    float* outS = outg + (size_t)N * V;

    dim3 tb(32, 8);
    dim3 tg((S + 31) / 32, (HH + 31) / 32);
    transposeW_bf16<<<tg, tb, 0, stream>>>(W, Wtb, S, HH);
    fused_row<<<N, THREADS, 0, stream>>>(hidden, pg, Wtb, bias, graph,
                                         outg, outS, S, V, NBR);
}